// Round 1
// baseline (13937.868 us; speedup 1.0000x reference)
//
#include <hip/hip_runtime.h>
#include <math.h>

#define TT 256
#define BB 32
#define EE 256
#define HH 512
#define G4 2048   // 4*H
#define LL 9

// ---------------- embedding gather: x0[t][b][e] = emb[ids[b][t]][e] ----------------
__global__ __launch_bounds__(256) void embed_kernel(const int* __restrict__ ids,
                                                    const float* __restrict__ emb,
                                                    float* __restrict__ x0) {
  int idx = blockIdx.x * blockDim.x + threadIdx.x;   // over T*B*(E/4)
  int e4 = idx & (EE / 4 - 1);
  int tb = idx / (EE / 4);
  if (tb >= TT * BB) return;
  int b = tb & (BB - 1);
  int t = tb / BB;
  int id = ids[b * TT + t];
  const float4* src = (const float4*)(emb + (size_t)id * EE);
  ((float4*)(x0 + ((size_t)t * BB + b) * EE))[e4] = src[e4];
}

// ---------------- pre-GEMM: out[m][g] = dot(A[m,:], W[g,:]) + bih[g] + bhh[g] ----------------
// A: (8192, K) row-major, W: (2048, K) row-major, out: (8192, 2048)
template <int K>
__global__ __launch_bounds__(256) void pre_gemm(const float* __restrict__ A,
                                                const float* __restrict__ W,
                                                const float* __restrict__ bih,
                                                const float* __restrict__ bhh,
                                                float* __restrict__ out) {
  __shared__ float As[32][132];
  __shared__ float Ws[32][132];
  int bm = blockIdx.x;   // 64
  int bn = blockIdx.y;   // 16
  int tid = threadIdx.x;
  int tx = tid & 15, ty = tid >> 4;
  float acc[8][8];
#pragma unroll
  for (int i = 0; i < 8; i++)
#pragma unroll
    for (int j = 0; j < 8; j++) acc[i][j] = 0.f;

  const int m0 = bm * 128, n0 = bn * 128;
  for (int k0 = 0; k0 < K; k0 += 32) {
#pragma unroll
    for (int i = 0; i < 4; i++) {
      int li = tid + i * 256;       // 0..1023
      int lm = li >> 3;             // 0..127
      int lk = (li & 7) << 2;       // 0..28
      float4 av = *(const float4*)(A + (size_t)(m0 + lm) * K + k0 + lk);
      As[lk + 0][lm] = av.x; As[lk + 1][lm] = av.y; As[lk + 2][lm] = av.z; As[lk + 3][lm] = av.w;
      float4 wv = *(const float4*)(W + (size_t)(n0 + lm) * K + k0 + lk);
      Ws[lk + 0][lm] = wv.x; Ws[lk + 1][lm] = wv.y; Ws[lk + 2][lm] = wv.z; Ws[lk + 3][lm] = wv.w;
    }
    __syncthreads();
#pragma unroll 8
    for (int kk = 0; kk < 32; kk++) {
      float a[8], w[8];
      *(float4*)&a[0] = *(const float4*)&As[kk][ty * 8];
      *(float4*)&a[4] = *(const float4*)&As[kk][ty * 8 + 4];
      *(float4*)&w[0] = *(const float4*)&Ws[kk][tx * 8];
      *(float4*)&w[4] = *(const float4*)&Ws[kk][tx * 8 + 4];
#pragma unroll
      for (int i = 0; i < 8; i++)
#pragma unroll
        for (int j = 0; j < 8; j++) acc[i][j] += a[i] * w[j];
    }
    __syncthreads();
  }
  int g0 = n0 + tx * 8;
  float bias[8];
#pragma unroll
  for (int j = 0; j < 8; j++) bias[j] = bih[g0 + j] + bhh[g0 + j];
#pragma unroll
  for (int i = 0; i < 8; i++) {
    int m = m0 + ty * 8 + i;
    float4 o0 = make_float4(acc[i][0] + bias[0], acc[i][1] + bias[1],
                            acc[i][2] + bias[2], acc[i][3] + bias[3]);
    float4 o1 = make_float4(acc[i][4] + bias[4], acc[i][5] + bias[5],
                            acc[i][6] + bias[6], acc[i][7] + bias[7]);
    *(float4*)(out + (size_t)m * G4 + g0) = o0;
    *(float4*)(out + (size_t)m * G4 + g0 + 4) = o1;
  }
}

// ---------------- one LSTM time step, both directions ----------------
// grid 256: wg>>7 = dir (0 fwd, 1 rev), (wg&127)*4 = hidden-unit base (Nj=4)
// 256 threads: 2-way K-split, 2x2 (gate-row x batch) register tiles, LDS gate buffer.
__global__ __launch_bounds__(256) void lstm_step(
    const float* __restrict__ pre_f, const float* __restrict__ pre_r,
    const float* __restrict__ whh_f, const float* __restrict__ whh_r,
    const float* __restrict__ h_prev, float* __restrict__ h_next,
    float* __restrict__ c_st, float* __restrict__ xcat, int t) {
  __shared__ float gs[2][16][32];   // [k-half][local gate row][b]
  int wg = blockIdx.x;
  int dir = wg >> 7;
  int j0 = (wg & 127) * 4;
  int seq = dir ? (TT - 1 - t) : t;
  const float* pre = dir ? pre_r : pre_f;
  const float* whh = dir ? whh_r : whh_f;
  const float* hp = h_prev + dir * (BB * HH);

  int tid = threadIdx.x;
  int ks = tid >> 7;            // K half
  int gi = (tid >> 4) & 7;      // row-pair index (16 local rows)
  int bi = tid & 15;            // b-pair index
  int lr0 = gi * 2;
  int q0 = lr0 >> 2, jj0 = lr0 & 3;       // local row -> (gate q, unit jj)
  int grow0 = q0 * HH + j0 + jj0;         // global gate row
  const float* w0 = whh + (size_t)grow0 * HH + ks * 256;
  const float* w1 = w0 + HH;              // grow0+1 (same gate block, jj0+1)
  const float* h0 = hp + (size_t)(2 * bi) * HH + ks * 256;
  const float* h1 = h0 + HH;
  float a00 = 0.f, a01 = 0.f, a10 = 0.f, a11 = 0.f;
#pragma unroll 4
  for (int k = 0; k < 256; k += 4) {
    float4 wv0 = *(const float4*)(w0 + k);
    float4 wv1 = *(const float4*)(w1 + k);
    float4 hv0 = *(const float4*)(h0 + k);
    float4 hv1 = *(const float4*)(h1 + k);
    a00 += wv0.x * hv0.x + wv0.y * hv0.y + wv0.z * hv0.z + wv0.w * hv0.w;
    a01 += wv0.x * hv1.x + wv0.y * hv1.y + wv0.z * hv1.z + wv0.w * hv1.w;
    a10 += wv1.x * hv0.x + wv1.y * hv0.y + wv1.z * hv0.z + wv1.w * hv0.w;
    a11 += wv1.x * hv1.x + wv1.y * hv1.y + wv1.z * hv1.z + wv1.w * hv1.w;
  }
  gs[ks][lr0][2 * bi] = a00;
  gs[ks][lr0][2 * bi + 1] = a01;
  gs[ks][lr0 + 1][2 * bi] = a10;
  gs[ks][lr0 + 1][2 * bi + 1] = a11;
  __syncthreads();
  if (tid < 128) {
    int jj = tid >> 5, b = tid & 31;
    int j = j0 + jj;
    size_t pbase = ((size_t)seq * BB + b) * (size_t)G4;
    float gv_i = gs[0][0 * 4 + jj][b] + gs[1][0 * 4 + jj][b] + pre[pbase + 0 * HH + j];
    float gv_f = gs[0][1 * 4 + jj][b] + gs[1][1 * 4 + jj][b] + pre[pbase + 1 * HH + j];
    float gv_g = gs[0][2 * 4 + jj][b] + gs[1][2 * 4 + jj][b] + pre[pbase + 2 * HH + j];
    float gv_o = gs[0][3 * 4 + jj][b] + gs[1][3 * 4 + jj][b] + pre[pbase + 3 * HH + j];
    float si = 1.f / (1.f + expf(-gv_i));
    float sf = 1.f / (1.f + expf(-gv_f));
    float so = 1.f / (1.f + expf(-gv_o));
    float tg = tanhf(gv_g);
    size_t ci = (size_t)dir * BB * HH + (size_t)b * HH + j;
    float c = sf * c_st[ci] + si * tg;
    c_st[ci] = c;
    float h = so * tanhf(c);
    h_next[ci] = h;
    xcat[((size_t)seq * BB + b) * 1024 + dir * HH + j] = h;
  }
}

// ---------------- classifier: em[b][t][l] = dot(x2[t][b][:], cw[l][:]) + cb[l] ----------------
__global__ __launch_bounds__(256) void cls_kernel(const float* __restrict__ x2,
                                                  const float* __restrict__ cw,
                                                  const float* __restrict__ cb,
                                                  float* __restrict__ em) {
  int idx = blockIdx.x * blockDim.x + threadIdx.x;
  if (idx >= BB * TT * LL) return;
  int l = idx % LL;
  int bt = idx / LL;
  int t = bt % TT;
  int b = bt / TT;
  const float4* xr = (const float4*)(x2 + ((size_t)t * BB + b) * 1024);
  const float4* wr = (const float4*)(cw + (size_t)l * 1024);
  float s = 0.f;
#pragma unroll 4
  for (int k = 0; k < 256; k++) {
    float4 xv = xr[k], wv = wr[k];
    s += xv.x * wv.x + xv.y * wv.y + xv.z * wv.z + xv.w * wv.w;
  }
  em[idx] = s + cb[l];
}

// ---------------- CRF NLL (single workgroup, sequential over T) ----------------
__global__ __launch_bounds__(320) void crf_kernel(const float* __restrict__ em,  // (B,T,L)
                                                  const int* __restrict__ labels,
                                                  const int* __restrict__ mask,
                                                  const float* __restrict__ start,
                                                  const float* __restrict__ end,
                                                  const float* __restrict__ trans,
                                                  float* __restrict__ loss_out) {
  __shared__ float al[32][9], tr[81], st[9], en[9];
  __shared__ float sc[32], red[32];
  __shared__ int pv[32];
  int tid = threadIdx.x;
  if (tid < 81) tr[tid] = trans[tid];
  if (tid < 9) { st[tid] = start[tid]; en[tid] = end[tid]; }
  __syncthreads();
  int j = tid >> 5, b = tid & 31;
  bool act = tid < 288;
  if (act) {
    int tg0 = labels[b * TT + 0];
    if (tg0 == -100) tg0 = 0;
    al[b][j] = st[j] + em[((size_t)b * TT + 0) * LL + j];
    if (j == 0) {
      sc[b] = st[tg0] + em[((size_t)b * TT + 0) * LL + tg0];
      pv[b] = tg0;
    }
  }
  __syncthreads();
  for (int t = 1; t < TT; t++) {
    float nxt = 0.f;
    int tg = 0;
    float mk = 0.f;
    if (act) {
      tg = labels[b * TT + t];
      if (tg == -100) tg = 0;
      mk = (float)mask[b * TT + t];
      float e_tj = em[((size_t)b * TT + t) * LL + j];
      float m = -1e30f;
#pragma unroll
      for (int i = 0; i < 9; i++) m = fmaxf(m, al[b][i] + tr[i * 9 + j]);
      float s = 0.f;
#pragma unroll
      for (int i = 0; i < 9; i++) s += expf(al[b][i] + tr[i * 9 + j] - m);
      nxt = m + logf(s) + e_tj;
    }
    __syncthreads();
    if (act) {
      if (j == 0 && mk > 0.f) {
        sc[b] += tr[pv[b] * 9 + tg] + em[((size_t)b * TT + t) * LL + tg];
      }
      if (mk > 0.f) al[b][j] = nxt;
      if (j == 0 && mk > 0.f) pv[b] = tg;
    }
    __syncthreads();
  }
  if (act && j == 0) {
    float m = -1e30f;
    for (int i = 0; i < 9; i++) m = fmaxf(m, al[b][i] + en[i]);
    float s = 0.f;
    for (int i = 0; i < 9; i++) s += expf(al[b][i] + en[i] - m);
    float logz = m + logf(s);
    red[b] = (sc[b] + en[pv[b]]) - logz;
  }
  __syncthreads();
  if (tid == 0) {
    float tot = 0.f;
    for (int bb = 0; bb < 32; bb++) tot += red[bb];
    loss_out[0] = -tot / 32.f;
  }
}

extern "C" void kernel_launch(void* const* d_in, const int* in_sizes, int n_in,
                              void* d_out, int out_size, void* d_ws, size_t ws_size,
                              hipStream_t stream) {
  (void)in_sizes; (void)n_in; (void)out_size; (void)ws_size;
  const int* ids = (const int*)d_in[0];
  const int* amask = (const int*)d_in[1];
  const int* labels = (const int*)d_in[2];
  const float* emb = (const float*)d_in[3];
  const float* wih0f = (const float*)d_in[4];
  const float* whh0f = (const float*)d_in[5];
  const float* bih0f = (const float*)d_in[6];
  const float* bhh0f = (const float*)d_in[7];
  const float* wih0r = (const float*)d_in[8];
  const float* whh0r = (const float*)d_in[9];
  const float* bih0r = (const float*)d_in[10];
  const float* bhh0r = (const float*)d_in[11];
  const float* wih1f = (const float*)d_in[12];
  const float* whh1f = (const float*)d_in[13];
  const float* bih1f = (const float*)d_in[14];
  const float* bhh1f = (const float*)d_in[15];
  const float* wih1r = (const float*)d_in[16];
  const float* whh1r = (const float*)d_in[17];
  const float* bih1r = (const float*)d_in[18];
  const float* bhh1r = (const float*)d_in[19];
  const float* cls_w = (const float*)d_in[20];
  const float* cls_b = (const float*)d_in[21];
  const float* crf_s = (const float*)d_in[22];
  const float* crf_e = (const float*)d_in[23];
  const float* crf_t = (const float*)d_in[24];

  float* ws = (float*)d_ws;
  float* x0 = ws;                        // T*B*E      = 2,097,152
  float* xc1 = x0 + 2097152;             // T*B*1024   = 8,388,608
  float* xc2 = xc1 + 8388608;            // T*B*1024   = 8,388,608
  float* pref = xc2 + 8388608;           // T*B*2048   = 16,777,216
  float* prer = pref + 16777216;         // T*B*2048   = 16,777,216
  float* ha = prer + 16777216;           // 2*B*H      = 32,768
  float* hb = ha + 32768;
  float* cs = hb + 32768;                // total ~210.5 MB

  float* loss = (float*)d_out;
  float* em = (float*)d_out + 1;

  embed_kernel<<<(TT * BB * (EE / 4) + 255) / 256, 256, 0, stream>>>(ids, emb, x0);

  // ---- layer 0 ----
  pre_gemm<EE><<<dim3(64, 16), 256, 0, stream>>>(x0, wih0f, bih0f, bhh0f, pref);
  pre_gemm<EE><<<dim3(64, 16), 256, 0, stream>>>(x0, wih0r, bih0r, bhh0r, prer);
  hipMemsetAsync(ha, 0, 2 * BB * HH * sizeof(float), stream);
  hipMemsetAsync(cs, 0, 2 * BB * HH * sizeof(float), stream);
  for (int t = 0; t < TT; t++) {
    lstm_step<<<256, 256, 0, stream>>>(pref, prer, whh0f, whh0r,
                                       (t & 1) ? hb : ha, (t & 1) ? ha : hb, cs, xc1, t);
  }
  // ---- layer 1 ----
  pre_gemm<1024><<<dim3(64, 16), 256, 0, stream>>>(xc1, wih1f, bih1f, bhh1f, pref);
  pre_gemm<1024><<<dim3(64, 16), 256, 0, stream>>>(xc1, wih1r, bih1r, bhh1r, prer);
  hipMemsetAsync(ha, 0, 2 * BB * HH * sizeof(float), stream);
  hipMemsetAsync(cs, 0, 2 * BB * HH * sizeof(float), stream);
  for (int t = 0; t < TT; t++) {
    lstm_step<<<256, 256, 0, stream>>>(pref, prer, whh1f, whh1r,
                                       (t & 1) ? hb : ha, (t & 1) ? ha : hb, cs, xc2, t);
  }

  cls_kernel<<<(BB * TT * LL + 255) / 256, 256, 0, stream>>>(xc2, cls_w, cls_b, em);
  crf_kernel<<<1, 320, 0, stream>>>(em, labels, amask, crf_s, crf_e, crf_t, loss);
}